// Round 3
// baseline (144.280 us; speedup 1.0000x reference)
//
#include <hip/hip_runtime.h>

// Heat_forward: Crank-Nicolson step for 5-point heat stencil, dense-matrix
// semantics (flat-index diagonals: +/-1 links wrap across grid-row ends).
//
// N_X=64, node=4096, BATCH=256, DT=1e-4, ALPHA=1
// r   = ALPHA*DT*N_X*N_X = 0.4096
// b   = (1-2r)x1 + (r/2)*nbr(x1) + 0.5*DT*(f0+f1)
// A1 u = b with A1 = (1+2r)I - (r/2)L  -> Jacobi:
//   u' = (b + (r/2)*nbr(u)) / (1+2r),  rho <= 2r/(1+2r) = 0.4504
// 28 iterations -> error ~2e-10, below f32 rounding.

#define NX    64
#define NODE  (NX * NX)          // 4096
#define NBATCH 256
#define HALO  64
#define LDSN  (NODE + 2 * HALO)  // 4224
#define NITER 28                 // must be even (ping-pong ends in u0)
#define NPT   16                 // nodes per thread (256 threads)

__global__ __launch_bounds__(256, 1)
void heat_cn_kernel(const float* __restrict__ in, float* __restrict__ out) {
    __shared__ float xs[LDSN];   // staged x1 (with zero halos)
    __shared__ float u0[LDSN];   // Jacobi ping
    __shared__ float u1[LDSN];   // Jacobi pong

    const int t = threadIdx.x;
    const int batch = blockIdx.x;

    const float r   = 0.4096f;
    const float r2  = 0.2048f;            // r/2
    const float d0  = 1.0f - 2.0f * r;    // A0 diagonal
    const float invd = 1.0f / (1.0f + 2.0f * r);
    const float hdt = 0.5f * 1e-4f;

    const float* __restrict__ src = in + (size_t)batch * NODE * 3;

    // zero the halos once (only interior is written afterwards)
    if (t < HALO) {
        xs[t] = 0.0f; xs[HALO + NODE + t] = 0.0f;
        u0[t] = 0.0f; u0[HALO + NODE + t] = 0.0f;
        u1[t] = 0.0f; u1[HALO + NODE + t] = 0.0f;
    }

    // load x1 into LDS, fold 0.5*DT*(f0+f1) into registers
    float fpart[NPT];
#pragma unroll
    for (int k = 0; k < NPT; ++k) {
        const int node = k * 256 + t;
        const float x1 = src[node * 3 + 0];
        const float f0 = src[node * 3 + 1];
        const float f1 = src[node * 3 + 2];
        xs[HALO + node] = x1;
        fpart[k] = hdt * (f0 + f1);
    }
    __syncthreads();

    // b = A0*x1 + fpart (registers); initial guess u0 = b/(1+2r)
    float bloc[NPT];
#pragma unroll
    for (int k = 0; k < NPT; ++k) {
        const int p = HALO + k * 256 + t;
        const float nb = xs[p - 1] + xs[p + 1] + xs[p - 64] + xs[p + 64];
        const float bv = d0 * xs[p] + r2 * nb + fpart[k];
        bloc[k] = bv;
        u0[p] = invd * bv;
    }
    __syncthreads();

    // Jacobi sweeps on fixed LDS buffers (compile-time addressing)
#define JSTEP(UC, UN)                                                   \
    {                                                                   \
        _Pragma("unroll")                                               \
        for (int k = 0; k < NPT; ++k) {                                 \
            const int p = HALO + k * 256 + t;                           \
            const float nb = UC[p - 1] + UC[p + 1] +                    \
                             UC[p - 64] + UC[p + 64];                   \
            UN[p] = invd * (bloc[k] + r2 * nb);                         \
        }                                                               \
        __syncthreads();                                                \
    }

    for (int it = 0; it < NITER / 2; ++it) {
        JSTEP(u0, u1)
        JSTEP(u1, u0)
    }
#undef JSTEP

    // write result, zeroing the Dirichlet border
    float* __restrict__ dst = out + (size_t)batch * NODE;
#pragma unroll
    for (int k = 0; k < NPT; ++k) {
        const int node = k * 256 + t;
        const int i = node >> 6;
        const int j = node & 63;
        float v = u0[HALO + node];
        if (i == 0 || i == NX - 1 || j == 0 || j == NX - 1) v = 0.0f;
        dst[node] = v;
    }
}

extern "C" void kernel_launch(void* const* d_in, const int* in_sizes, int n_in,
                              void* d_out, int out_size, void* d_ws, size_t ws_size,
                              hipStream_t stream) {
    (void)in_sizes; (void)n_in; (void)d_ws; (void)ws_size; (void)out_size;
    const float* in = (const float*)d_in[0];   // (256, 64, 64, 3) f32
    float* out = (float*)d_out;                // (256, 64, 64) f32
    heat_cn_kernel<<<NBATCH, 256, 0, stream>>>(in, out);
}

// Round 4
// 136.515 us; speedup vs baseline: 1.0569x; 1.0569x over previous
//
#include <hip/hip_runtime.h>

// Heat_forward: Crank-Nicolson step for 5-point heat stencil, dense-matrix
// semantics (flat-index diagonals: +/-1 links wrap across grid-row ends).
//
// N_X=64, node=4096, BATCH=256, DT=1e-4, ALPHA=1
// r   = ALPHA*DT*N_X*N_X = 0.4096
// b   = (1-2r)x1 + (r/2)*nbr(x1) + 0.5*DT*(f0+f1)
// A1 u = b with A1 = (1+2r)I - (r/2)L  -> Jacobi:
//   u' = (b + (r/2)*nbr(u)) / (1+2r),  rho <= 2r/(1+2r) = 0.4504
// 16 iterations -> iter error ~7e-6, far below the ~4e-3 error the dense
// f32 LU reference itself carries (measured absmax 0.0039 at NITER=28).

#define NX    64
#define NODE  (NX * NX)          // 4096
#define NBATCH 256
#define HALO  64
#define LDSN  (NODE + 2 * HALO)  // 4224
#define NITER 16                 // must be even (ping-pong ends in u0)
#define NT    512                // threads per block (8 waves/CU)
#define NPT   (NODE / NT)        // 8 nodes per thread

__global__ __launch_bounds__(NT, 1)
void heat_cn_kernel(const float* __restrict__ in, float* __restrict__ out) {
    __shared__ float xs[LDSN];   // staged x1 (with zero halos)
    __shared__ float u0[LDSN];   // Jacobi ping
    __shared__ float u1[LDSN];   // Jacobi pong

    const int t = threadIdx.x;
    const int batch = blockIdx.x;

    const float r    = 0.4096f;
    const float r2   = 0.2048f;             // r/2
    const float d0   = 1.0f - 2.0f * r;     // A0 diagonal
    const float invd = 1.0f / (1.0f + 2.0f * r);
    const float cc   = invd * r2;           // fused sweep coefficient
    const float hdt  = 0.5f * 1e-4f;

    const float* __restrict__ src = in + (size_t)batch * NODE * 3;

    // zero the halos once (only interior is written afterwards)
    if (t < HALO) {
        xs[t] = 0.0f; xs[HALO + NODE + t] = 0.0f;
        u0[t] = 0.0f; u0[HALO + NODE + t] = 0.0f;
        u1[t] = 0.0f; u1[HALO + NODE + t] = 0.0f;
    }

    // load x1 into LDS, fold 0.5*DT*(f0+f1) into registers
    float fpart[NPT];
#pragma unroll
    for (int k = 0; k < NPT; ++k) {
        const int node = k * NT + t;
        const float x1 = src[node * 3 + 0];
        const float f0 = src[node * 3 + 1];
        const float f1 = src[node * 3 + 2];
        xs[HALO + node] = x1;
        fpart[k] = hdt * (f0 + f1);
    }
    __syncthreads();

    // b = A0*x1 + fpart; keep invd*b in registers; initial guess u0 = invd*b
    float bsc[NPT];                 // invd * b
#pragma unroll
    for (int k = 0; k < NPT; ++k) {
        const int p = HALO + k * NT + t;
        const float nb = xs[p - 1] + xs[p + 1] + xs[p - 64] + xs[p + 64];
        const float bv = d0 * xs[p] + r2 * nb + fpart[k];
        bsc[k] = invd * bv;
        u0[p] = invd * bv;
    }
    __syncthreads();

    // Jacobi sweeps on fixed LDS buffers (compile-time addressing)
    // u' = invd*b + (invd*r/2)*nbr(u)  ->  one fma per node
#define JSTEP(UC, UN)                                                   \
    {                                                                   \
        _Pragma("unroll")                                               \
        for (int k = 0; k < NPT; ++k) {                                 \
            const int p = HALO + k * NT + t;                            \
            const float nb = UC[p - 1] + UC[p + 1] +                    \
                             UC[p - 64] + UC[p + 64];                   \
            UN[p] = fmaf(cc, nb, bsc[k]);                               \
        }                                                               \
        __syncthreads();                                                \
    }

    for (int it = 0; it < NITER / 2; ++it) {
        JSTEP(u0, u1)
        JSTEP(u1, u0)
    }
#undef JSTEP

    // write result, zeroing the Dirichlet border
    float* __restrict__ dst = out + (size_t)batch * NODE;
#pragma unroll
    for (int k = 0; k < NPT; ++k) {
        const int node = k * NT + t;
        const int i = node >> 6;
        const int j = node & 63;
        float v = u0[HALO + node];
        if (i == 0 || i == NX - 1 || j == 0 || j == NX - 1) v = 0.0f;
        dst[node] = v;
    }
}

extern "C" void kernel_launch(void* const* d_in, const int* in_sizes, int n_in,
                              void* d_out, int out_size, void* d_ws, size_t ws_size,
                              hipStream_t stream) {
    (void)in_sizes; (void)n_in; (void)d_ws; (void)ws_size; (void)out_size;
    const float* in = (const float*)d_in[0];   // (256, 64, 64, 3) f32
    float* out = (float*)d_out;                // (256, 64, 64) f32
    heat_cn_kernel<<<NBATCH, NT, 0, stream>>>(in, out);
}

// Round 6
// 132.308 us; speedup vs baseline: 1.0905x; 1.0318x over previous
//
#include <hip/hip_runtime.h>

// Heat_forward: Crank-Nicolson step, dense-matrix semantics (flat-index
// diagonals: +/-1 wraps across grid-row ends). Solve A1 u = b via
// CHEBYSHEV-accelerated Jacobi:
//   u' = M u + g,  M = cc*L (cc = (r/2)/(1+2r)), g = b/(1+2r)
//   rho(M) <= 4cc = 0.45031, sigma = rho/(1+sqrt(1-rho^2)) = 0.238
//   x_{k+1} = w_{k+1} (M x_k + g - x_{k-1}) + x_{k-1}
//   w_2 = 2/(2-rho^2), w_{k+1} = 1/(1 - (rho^2/4) w_k)
// 8 sweeps -> error ~2e-5 * ||e0||, far below the ~3.9e-3 f32-LU error the
// reference itself carries. x_{k-1} at a thread's own nodes is kept in
// REGISTERS (written by this thread one sweep earlier) -> still only
// 4 LDS reads + 1 LDS write per node per sweep.

#define NX    64
#define NODE  (NX * NX)          // 4096
#define NBATCH 256
#define HALO  64
#define LDSN  (NODE + 2 * HALO)  // 4224
#define NT    512                // threads per block (8 waves/CU)
#define NPT   (NODE / NT)        // 8 nodes per thread

// Chebyshev weights for rho^2 = 0.20277725 (rho = 0.45030782)
#define W2 1.1128240f
#define W3 1.0597800f
#define W4 1.0567752f
#define W5 1.0566050f
#define W6 1.0565953f
#define W7 1.0565948f
#define W8 1.0565947f

__global__ __launch_bounds__(NT, 1)
void heat_cn_kernel(const float* __restrict__ in, float* __restrict__ out) {
    __shared__ float xs[LDSN];   // staged x1 (with zero halos)
    __shared__ float u0[LDSN];   // ping  (x0, x2, x4, x6, x8)
    __shared__ float u1[LDSN];   // pong  (x1, x3, x5, x7)

    const int t = threadIdx.x;
    const int batch = blockIdx.x;

    const float r    = 0.4096f;
    const float r2   = 0.2048f;             // r/2
    const float d0   = 1.0f - 2.0f * r;     // A0 diagonal
    const float invd = 1.0f / (1.0f + 2.0f * r);
    const float cc   = invd * r2;           // Jacobi stencil coefficient
    const float hdt  = 0.5f * 1e-4f;

    const float* __restrict__ src = in + (size_t)batch * NODE * 3;

    // zero the halos once (only interior is written afterwards)
    if (t < HALO) {
        xs[t] = 0.0f; xs[HALO + NODE + t] = 0.0f;
        u0[t] = 0.0f; u0[HALO + NODE + t] = 0.0f;
        u1[t] = 0.0f; u1[HALO + NODE + t] = 0.0f;
    }

    // load x1 into LDS, fold 0.5*DT*(f0+f1) into registers
    float fpart[NPT];
#pragma unroll
    for (int k = 0; k < NPT; ++k) {
        const int node = k * NT + t;
        const float x1 = src[node * 3 + 0];
        const float f0 = src[node * 3 + 1];
        const float f1 = src[node * 3 + 2];
        xs[HALO + node] = x1;
        fpart[k] = hdt * (f0 + f1);
    }
    __syncthreads();

    // g = invd*b;  x0 = g (LDS u0 + registers)
    float bsc[NPT];     // g
    float rcur[NPT];    // x_k     at my nodes
    float rprev[NPT];   // x_{k-1} at my nodes
#pragma unroll
    for (int k = 0; k < NPT; ++k) {
        const int p = HALO + k * NT + t;
        const float nb = xs[p - 1] + xs[p + 1] + xs[p - 64] + xs[p + 64];
        const float bv = d0 * xs[p] + r2 * nb + fpart[k];
        const float g = invd * bv;
        bsc[k] = g;
        rcur[k] = g;
        u0[p] = g;
    }
    __syncthreads();

    // sweep 1 (w=1): x1 = M x0 + g, from u0 -> u1
#pragma unroll
    for (int k = 0; k < NPT; ++k) {
        const int p = HALO + k * NT + t;
        const float nb = u0[p - 1] + u0[p + 1] + u0[p - 64] + u0[p + 64];
        const float xn = fmaf(cc, nb, bsc[k]);
        rprev[k] = rcur[k];
        rcur[k] = xn;
        u1[p] = xn;
    }
    __syncthreads();

    // sweeps 2..8: x_{k+1} = w*(M x_k + g - x_{k-1}) + x_{k-1}
#define CHEB(UC, UN, W)                                                 \
    {                                                                   \
        _Pragma("unroll")                                               \
        for (int k = 0; k < NPT; ++k) {                                 \
            const int p = HALO + k * NT + t;                            \
            const float nb = UC[p - 1] + UC[p + 1] +                    \
                             UC[p - 64] + UC[p + 64];                   \
            const float jac = fmaf(cc, nb, bsc[k]);                     \
            const float xn = fmaf(W, jac - rprev[k], rprev[k]);         \
            rprev[k] = rcur[k];                                         \
            rcur[k] = xn;                                               \
            UN[p] = xn;                                                 \
        }                                                               \
        __syncthreads();                                                \
    }

    CHEB(u1, u0, W2)   // x2 -> u0
    CHEB(u0, u1, W3)   // x3 -> u1
    CHEB(u1, u0, W4)   // x4 -> u0
    CHEB(u0, u1, W5)   // x5 -> u1
    CHEB(u1, u0, W6)   // x6 -> u0
    CHEB(u0, u1, W7)   // x7 -> u1
    CHEB(u1, u0, W8)   // x8 -> u0  (final)
#undef CHEB

    // write result, zeroing the Dirichlet border
    float* __restrict__ dst = out + (size_t)batch * NODE;
#pragma unroll
    for (int k = 0; k < NPT; ++k) {
        const int node = k * NT + t;
        const int i = node >> 6;
        const int j = node & 63;
        float v = rcur[k];
        if (i == 0 || i == NX - 1 || j == 0 || j == NX - 1) v = 0.0f;
        dst[node] = v;
    }
}

extern "C" void kernel_launch(void* const* d_in, const int* in_sizes, int n_in,
                              void* d_out, int out_size, void* d_ws, size_t ws_size,
                              hipStream_t stream) {
    (void)in_sizes; (void)n_in; (void)d_ws; (void)ws_size; (void)out_size;
    const float* in = (const float*)d_in[0];   // (256, 64, 64, 3) f32
    float* out = (float*)d_out;                // (256, 64, 64) f32
    heat_cn_kernel<<<NBATCH, NT, 0, stream>>>(in, out);
}